// Round 6
// baseline (295.589 us; speedup 1.0000x reference)
//
#include <hip/hip_runtime.h>
#include <hip/hip_bf16.h>

typedef __attribute__((ext_vector_type(8))) short short8;
typedef __attribute__((ext_vector_type(4))) float f32x4;

#define B_T 200
#define B_D 128

static __device__ __forceinline__ short f2bf(float f) {
  // round-to-nearest-even f32 -> bf16 (inputs are finite)
  unsigned u = __builtin_bit_cast(unsigned, f);
  u += 0x7fffu + ((u >> 16) & 1u);
  return (short)(u >> 16);
}
static __device__ __forceinline__ float bf2f(short s) {
  unsigned u = ((unsigned)(unsigned short)s) << 16;
  return __builtin_bit_cast(float, u);
}
static __device__ __forceinline__ short8 cvt8(f32x4 a, f32x4 b) {
  short8 t;
  t[0] = f2bf(a[0]); t[1] = f2bf(a[1]); t[2] = f2bf(a[2]); t[3] = f2bf(a[3]);
  t[4] = f2bf(b[0]); t[5] = f2bf(b[1]); t[6] = f2bf(b[2]); t[7] = f2bf(b[3]);
  return t;
}

// 512 threads (8 waves). NO min-waves arg: with (512,4) the compiler caps
// VGPR=64 and spills 190 MB (R1/R3); with (512,2) the runtime clamps residency
// to 1 block/CU (R5, Occupancy 24%). Natural allocation = 84 VGPR -> 6
// waves/SIMD cap -> ~3 blocks/CU resident.
__global__ __launch_bounds__(512)
void ta_fused(const float* __restrict__ x,      // [B,T,D]
              const float* __restrict__ cand,   // [B,D]
              const void*  __restrict__ maskp,  // [B,T] int32 or 1-byte bool
              const float* __restrict__ W1,     // [384,128]
              const float* __restrict__ b1,     // [128]
              const float* __restrict__ ap,     // [1]
              const float* __restrict__ W2,     // [128]
              const float* __restrict__ b2p,    // [1]
              float* __restrict__ out)          // [B,D]
{
  // 32 KB region: wbt (bf16 Wb, fragment-linear) until end of phase 2;
  // aliased by pout (8x128 f32 partial outputs) from phase 4 on (two
  // barriers separate last wbt read from first pout write).
  __shared__ __align__(16) char smem_raw[B_D * B_D * 2];
  short* wbt = (short*)smem_raw;
  float (*pout)[B_D] = (float (*)[B_D])smem_raw;
  __shared__ float part[4][B_D];   // beta partials (b1 folded into part[0])
  __shared__ float w2_lds[B_D];
  __shared__ float scores[208];
  __shared__ float red[16];

  const int b    = blockIdx.x;
  const int tid  = threadIdx.x;
  const int lane = tid & 63;
  const int wv   = tid >> 6;      // 0..7
  const int l15  = lane & 15;
  const int g    = lane >> 4;     // 0..3

  // ---- issue the full x stream FIRST (overlaps all of phase 1)
  const int row0 = wv * 16 + l15;                         // <= 127 < 200
  int row1 = (8 + wv) * 16 + l15; if (row1 > B_T - 1) row1 = B_T - 1;
  const float* xr0 = x + ((size_t)b * B_T + row0) * B_D + g * 8;
  const float* xr1 = x + ((size_t)b * B_T + row1) * B_D + g * 8;
  f32x4 r00 = *(const f32x4*)(xr0 +  0), r01 = *(const f32x4*)(xr0 +  4);
  f32x4 r02 = *(const f32x4*)(xr0 + 32), r03 = *(const f32x4*)(xr0 + 36);
  f32x4 r04 = *(const f32x4*)(xr0 + 64), r05 = *(const f32x4*)(xr0 + 68);
  f32x4 r06 = *(const f32x4*)(xr0 + 96), r07 = *(const f32x4*)(xr0 + 100);
  f32x4 r10 = *(const f32x4*)(xr1 +  0), r11 = *(const f32x4*)(xr1 +  4);
  f32x4 r12 = *(const f32x4*)(xr1 + 32), r13 = *(const f32x4*)(xr1 + 36);
  f32x4 r14 = *(const f32x4*)(xr1 + 64), r15 = *(const f32x4*)(xr1 + 68);
  f32x4 r16 = *(const f32x4*)(xr1 + 96), r17 = *(const f32x4*)(xr1 + 100);

  // ---- mask dtype probe: every wave scans the SAME 512 B -> block-consistent,
  // no LDS, no barrier. int32 storage has all off-aligned bytes == 0.
  int flag1b;
  {
    const unsigned char* mb = (const unsigned char*)maskp;
    unsigned long long v8 = *(const unsigned long long*)(mb + lane * 8);
    flag1b = __any((v8 & 0xFFFFFF00FFFFFF00ull) != 0ull);
  }
  // hoist this block's mask row (off the softmax critical path)
  bool mk = false;
  if (tid < B_T) {
    if (flag1b) mk = ((const unsigned char*)maskp)[(size_t)b * B_T + tid] != 0;
    else        mk = ((const int*)maskp)[(size_t)b * B_T + tid] != 0;
  }

  if (tid < B_D) w2_lds[tid] = W2[tid];

  // ---- phase 1: Wb = W1a + c (*) W1c -> wbt ; beta partials -> part
  const float* cb = cand + (size_t)b * B_D;
  {
    const int j = tid & 127;          // fixed per thread (512 % 128 == 0)
    // wbt build: each thread produces one k-octet (8 consecutive k) for its j,
    // one ds_write_b128 at consecutive-lane addresses -> conflict-free.
    #pragma unroll 2
    for (int it = 0; it < 4; ++it) {
      const int ko = it * 4 + (tid >> 7);   // 0..15
      const int k0 = ko * 8;
      short8 t;
      #pragma unroll
      for (int e = 0; e < 8; ++e) {
        float c  = cb[k0 + e];
        float wa = W1[(size_t)(k0 + e) * B_D + j];
        float wc = W1[(size_t)(256 + k0 + e) * B_D + j];
        t[e] = f2bf(wa + c * wc);
      }
      *(short8*)&wbt[(ko * B_D + j) * 8] = t;
    }
    // part[q][j] = (q==0 ? b1[j] : 0) + sum_{k in q-slice} c[k]*W1b[k][j]
    const int q = tid >> 7;           // 0..3
    float s = (q == 0) ? b1[j] : 0.f;
    const float* w1b = W1 + (size_t)(B_D + q * 32) * B_D + j;
    #pragma unroll 4
    for (int k = 0; k < 32; ++k) s += cb[q * 32 + k] * w1b[(size_t)k * B_D];
    part[q][j] = s;
  }
  __syncthreads();   // the ONLY barrier before MFMA

  // ---- convert x -> A fragments (frees the 64 staging VGPRs)
  short8 af00 = cvt8(r00, r01), af01 = cvt8(r02, r03);
  short8 af02 = cvt8(r04, r05), af03 = cvt8(r06, r07);
  short8 af10 = cvt8(r10, r11), af11 = cvt8(r12, r13);
  short8 af12 = cvt8(r14, r15), af13 = cvt8(r16, r17);

  float betaL[8], w2L[8];
  #pragma unroll
  for (int nt = 0; nt < 8; ++nt) {
    int col = nt * 16 + l15;
    betaL[nt] = part[0][col] + part[1][col] + part[2][col] + part[3][col];
    w2L[nt]   = w2_lds[col];
  }
  const float alpha = ap[0];
  const float b2    = b2p[0];

  // ---- phase 2: per-tile MFMA + fused PReLU + W2 epilogue -> scores
#define TILE_SCORE(A0, A1, A2, A3, TB) do {                                   \
    float sc[4] = {0.f, 0.f, 0.f, 0.f};                                       \
    _Pragma("unroll")                                                         \
    for (int nt = 0; nt < 8; ++nt) {                                          \
      f32x4 acc = {0.f, 0.f, 0.f, 0.f};                                       \
      const short8* wp = (const short8*)wbt + g * B_D + nt * 16 + l15;        \
      acc = __builtin_amdgcn_mfma_f32_16x16x32_bf16(A0, wp[0],    acc, 0,0,0);\
      acc = __builtin_amdgcn_mfma_f32_16x16x32_bf16(A1, wp[512],  acc, 0,0,0);\
      acc = __builtin_amdgcn_mfma_f32_16x16x32_bf16(A2, wp[1024], acc, 0,0,0);\
      acc = __builtin_amdgcn_mfma_f32_16x16x32_bf16(A3, wp[1536], acc, 0,0,0);\
      _Pragma("unroll")                                                       \
      for (int r = 0; r < 4; ++r) {                                           \
        float h = acc[r] + betaL[nt];                                         \
        float p = (h >= 0.f) ? h : alpha * h;                                 \
        sc[r] += p * w2L[nt];                                                 \
      }                                                                       \
    }                                                                         \
    _Pragma("unroll")                                                         \
    for (int r = 0; r < 4; ++r) {                                             \
      float v = sc[r];                                                        \
      v += __shfl_xor(v, 1, 16); v += __shfl_xor(v, 2, 16);                   \
      v += __shfl_xor(v, 4, 16); v += __shfl_xor(v, 8, 16);                   \
      if (l15 == 0) scores[(TB) + g * 4 + r] = v + b2;                        \
    }                                                                         \
  } while (0)

  const int ntile = (wv < 5) ? 2 : 1;
  TILE_SCORE(af00, af01, af02, af03, wv * 16);
  if (ntile > 1) TILE_SCORE(af10, af11, af12, af13, (8 + wv) * 16);
  __syncthreads();

  // ---- phase 3: masked softmax over t
  {
    float s = (tid < B_T && mk) ? scores[tid] : -INFINITY;
    float v = s;
    #pragma unroll
    for (int m = 32; m >= 1; m >>= 1) v = fmaxf(v, __shfl_xor(v, m, 64));
    if (lane == 0) red[wv] = v;
    __syncthreads();
    float mx = -INFINITY;
    #pragma unroll
    for (int i = 0; i < 8; ++i) mx = fmaxf(mx, red[i]);
    float e = mk ? __expf(s - mx) : 0.f;
    float sv = e;
    #pragma unroll
    for (int m = 32; m >= 1; m >>= 1) sv += __shfl_xor(sv, m, 64);
    if (lane == 0) red[8 + wv] = sv;
    __syncthreads();
    float Z = 0.f;
    #pragma unroll
    for (int i = 0; i < 8; ++i) Z += red[8 + i];
    if (tid < 208) scores[tid] = e / Z;    // tid in [200,208): e==0 -> 0
  }
  __syncthreads();   // after this barrier wbt is dead -> pout may alias it

  // ---- phase 4: out[b,:] = sum_t w[t]*x[t,:] from held A fragments
  {
    float w0 = scores[wv * 16 + l15];
    float w1 = (ntile > 1) ? scores[(8 + wv) * 16 + l15] : 0.f;
    #pragma unroll
    for (int ks = 0; ks < 4; ++ks) {
      short8 t0 = (ks == 0) ? af00 : (ks == 1) ? af01 : (ks == 2) ? af02 : af03;
      short8 t1 = (ks == 0) ? af10 : (ks == 1) ? af11 : (ks == 2) ? af12 : af13;
      float accw[8];
      #pragma unroll
      for (int e = 0; e < 8; ++e) accw[e] = w0 * bf2f(t0[e]) + w1 * bf2f(t1[e]);
      #pragma unroll
      for (int e = 0; e < 8; ++e) {
        float v = accw[e];
        v += __shfl_xor(v, 1, 16); v += __shfl_xor(v, 2, 16);
        v += __shfl_xor(v, 4, 16); v += __shfl_xor(v, 8, 16);
        if (l15 == 0) pout[wv][ks * 32 + g * 8 + e] = v;
      }
    }
  }
  __syncthreads();
  if (tid < B_D) {
    float s = 0.f;
    #pragma unroll
    for (int i = 0; i < 8; ++i) s += pout[i][tid];
    out[(size_t)b * B_D + tid] = s;
  }
}

extern "C" void kernel_launch(void* const* d_in, const int* in_sizes, int n_in,
                              void* d_out, int out_size, void* d_ws, size_t ws_size,
                              hipStream_t stream) {
  const float* x    = (const float*)d_in[0];
  const float* cand = (const float*)d_in[1];
  const void*  mask = d_in[2];
  const float* W1   = (const float*)d_in[3];
  const float* b1   = (const float*)d_in[4];
  const float* a    = (const float*)d_in[5];
  const float* W2   = (const float*)d_in[6];
  const float* b2   = (const float*)d_in[7];
  float* out = (float*)d_out;
  const int B = in_sizes[1] / B_D;   // candidate is [B,128]
  ta_fused<<<B, 512, 0, stream>>>(x, cand, mask, W1, b1, a, W2, b2, out);
}

// Round 7
// 163.210 us; speedup vs baseline: 1.8111x; 1.8111x over previous
//
#include <hip/hip_runtime.h>
#include <hip/hip_bf16.h>

typedef __attribute__((ext_vector_type(8))) short short8;
typedef __attribute__((ext_vector_type(4))) float f32x4;

#define B_T 200
#define B_D 128

static __device__ __forceinline__ short f2bf(float f) {
  // round-to-nearest-even f32 -> bf16 (inputs are finite)
  unsigned u = __builtin_bit_cast(unsigned, f);
  u += 0x7fffu + ((u >> 16) & 1u);
  return (short)(u >> 16);
}
static __device__ __forceinline__ short8 cvt8(f32x4 a, f32x4 b) {
  short8 t;
  t[0] = f2bf(a[0]); t[1] = f2bf(a[1]); t[2] = f2bf(a[2]); t[3] = f2bf(a[3]);
  t[4] = f2bf(b[0]); t[5] = f2bf(b[1]); t[6] = f2bf(b[2]); t[7] = f2bf(b[3]);
  return t;
}

// 512 threads / 8 waves. (512,4) -> total (VGPR+acc) cap 128/wave: the only
// config measured with >=2 blocks/CU resident (R2). Per-tile register demand
// in this re-read design is ~80, so no spill at the 128 cap.
__global__ __launch_bounds__(512, 4)
void ta_fused(const float* __restrict__ x,      // [B,T,D]
              const float* __restrict__ cand,   // [B,D]
              const void*  __restrict__ maskp,  // [B,T] int32 or 1-byte bool
              const float* __restrict__ W1,     // [384,128]
              const float* __restrict__ b1,     // [128]
              const float* __restrict__ ap,     // [1]
              const float* __restrict__ W2,     // [128]
              const float* __restrict__ b2p,    // [1] (unused: softmax shift-invariant)
              float* __restrict__ out)          // [B,D]
{
  // wbt fragment-linear bf16: element (k,j) at ((k>>3)*128 + j)*8 + (k&7).
  __shared__ __align__(16) short wbt[B_D * B_D];
  __shared__ float part[4][B_D];   // beta partials; reused for phase-C partials
  __shared__ float w2_lds[B_D];
  __shared__ float scores[208];
  __shared__ float red[16];

  const int b    = blockIdx.x;
  const int tid  = threadIdx.x;
  const int lane = tid & 63;
  const int wv   = tid >> 6;      // 0..7
  const int l15  = lane & 15;
  const int g    = lane >> 4;     // 0..3

  // ---- mask dtype probe: every wave scans the SAME 512 B -> block-consistent,
  // no LDS, no barrier. int32 storage has all off-aligned bytes == 0.
  int flag1b;
  {
    const unsigned char* mb = (const unsigned char*)maskp;
    unsigned long long v8 = *(const unsigned long long*)(mb + lane * 8);
    flag1b = __any((v8 & 0xFFFFFF00FFFFFF00ull) != 0ull);
  }
  // hoist this block's mask row (off the softmax critical path)
  bool mk = false;
  if (tid < B_T) {
    if (flag1b) mk = ((const unsigned char*)maskp)[(size_t)b * B_T + tid] != 0;
    else        mk = ((const int*)maskp)[(size_t)b * B_T + tid] != 0;
  }

  if (tid < B_D) w2_lds[tid] = W2[tid];

  // ---- phase 1: Wb = W1a + c (*) W1c -> wbt ; beta partials -> part
  const float* cb = cand + (size_t)b * B_D;
  {
    const int j = tid & 127;          // fixed per thread (512 % 128 == 0)
    // each thread produces one k-octet (8 consecutive k) for its j:
    // one ds_write_b128 at consecutive-lane addresses -> conflict-free.
    #pragma unroll 2
    for (int it = 0; it < 4; ++it) {
      const int ko = it * 4 + (tid >> 7);   // 0..15
      const int k0 = ko * 8;
      short8 t;
      #pragma unroll
      for (int e = 0; e < 8; ++e) {
        float c  = cb[k0 + e];
        float wa = W1[(size_t)(k0 + e) * B_D + j];
        float wc = W1[(size_t)(256 + k0 + e) * B_D + j];
        t[e] = f2bf(wa + c * wc);
      }
      *(short8*)&wbt[(ko * B_D + j) * 8] = t;
    }
    // part[q][j] = (q==0 ? b1[j] : 0) + sum_{k in q-slice} c[k]*W1b[k][j]
    const int q = tid >> 7;           // 0..3
    float s = (q == 0) ? b1[j] : 0.f;
    const float* w1b = W1 + (size_t)(B_D + q * 32) * B_D + j;
    #pragma unroll 4
    for (int k = 0; k < 32; ++k) s += cb[q * 32 + k] * w1b[(size_t)k * B_D];
    part[q][j] = s;
  }
  __syncthreads();   // the ONLY barrier before MFMA

  float betaL[8], w2L[8];
  #pragma unroll
  for (int nt = 0; nt < 8; ++nt) {
    int col = nt * 16 + l15;
    betaL[nt] = part[0][col] + part[1][col] + part[2][col] + part[3][col];
    w2L[nt]   = w2_lds[col];
  }
  const float alpha = ap[0];

  // ---- phase A: per-tile {load x, cvt, MFMA, PReLU+W2 epilogue} -> scores.
  // x tile is RELEASED after use (re-read in phase C from L2) -> low regs.
#define TILE_SCORE(MT) do {                                                   \
    int row = (MT) * 16 + l15; if (row > B_T - 1) row = B_T - 1;              \
    const float* xr = x + ((size_t)b * B_T + row) * B_D + g * 8;              \
    f32x4 p0 = *(const f32x4*)(xr +  0), p1 = *(const f32x4*)(xr +   4);      \
    f32x4 p2 = *(const f32x4*)(xr + 32), p3 = *(const f32x4*)(xr +  36);      \
    f32x4 p4 = *(const f32x4*)(xr + 64), p5 = *(const f32x4*)(xr +  68);      \
    f32x4 p6 = *(const f32x4*)(xr + 96), p7 = *(const f32x4*)(xr + 100);      \
    short8 a0 = cvt8(p0, p1), a1 = cvt8(p2, p3);                              \
    short8 a2 = cvt8(p4, p5), a3 = cvt8(p6, p7);                              \
    float sc[4] = {0.f, 0.f, 0.f, 0.f};                                       \
    _Pragma("unroll")                                                         \
    for (int nt = 0; nt < 8; ++nt) {                                          \
      f32x4 acc = {0.f, 0.f, 0.f, 0.f};                                       \
      const short8* wp = (const short8*)wbt + g * B_D + nt * 16 + l15;        \
      acc = __builtin_amdgcn_mfma_f32_16x16x32_bf16(a0, wp[0],    acc, 0,0,0);\
      acc = __builtin_amdgcn_mfma_f32_16x16x32_bf16(a1, wp[512],  acc, 0,0,0);\
      acc = __builtin_amdgcn_mfma_f32_16x16x32_bf16(a2, wp[1024], acc, 0,0,0);\
      acc = __builtin_amdgcn_mfma_f32_16x16x32_bf16(a3, wp[1536], acc, 0,0,0);\
      _Pragma("unroll")                                                       \
      for (int r = 0; r < 4; ++r) {                                           \
        float h = acc[r] + betaL[nt];                                         \
        float p = (h >= 0.f) ? h : alpha * h;                                 \
        sc[r] += p * w2L[nt];                                                 \
      }                                                                       \
    }                                                                         \
    _Pragma("unroll")                                                         \
    for (int r = 0; r < 4; ++r) {                                             \
      float v = sc[r];                                                        \
      v += __shfl_xor(v, 1, 16); v += __shfl_xor(v, 2, 16);                   \
      v += __shfl_xor(v, 4, 16); v += __shfl_xor(v, 8, 16);                   \
      if (l15 == 0) scores[(MT) * 16 + g * 4 + r] = v;                        \
    }                                                                         \
  } while (0)

  TILE_SCORE(wv);
  if (wv < 5) TILE_SCORE(8 + wv);
#undef TILE_SCORE
  __syncthreads();

  // ---- phase B: masked softmax over t (b2 omitted: softmax shift-invariant)
  {
    float s = (tid < B_T && mk) ? scores[tid] : -INFINITY;
    float v = s;
    #pragma unroll
    for (int m = 32; m >= 1; m >>= 1) v = fmaxf(v, __shfl_xor(v, m, 64));
    if (lane == 0) red[wv] = v;
    __syncthreads();
    float mx = -INFINITY;
    #pragma unroll
    for (int i = 0; i < 8; ++i) mx = fmaxf(mx, red[i]);
    float e = mk ? __expf(s - mx) : 0.f;
    float sv = e;
    #pragma unroll
    for (int m = 32; m >= 1; m >>= 1) sv += __shfl_xor(sv, m, 64);
    if (lane == 0) red[8 + wv] = sv;
    __syncthreads();
    float Z = 0.f;
    #pragma unroll
    for (int i = 0; i < 8; ++i) Z += red[8 + i];
    if (tid < 208) scores[tid] = e / Z;    // tid in [200,208): e==0 -> 0
  }
  __syncthreads();

  // ---- phase C: out[b,:] = sum_t w[t]*x[t,:], re-reading x (L2-hot).
  // thread (q = tid>>7, d = tid&127) accumulates t in [q*50, q*50+50).
  {
    const int d = tid & 127;
    const int q = tid >> 7;
    const float* xc = x + ((size_t)b * B_T + q * 50) * B_D + d;
    float s = 0.f;
    #pragma unroll 5
    for (int t = 0; t < 50; ++t) s = fmaf(scores[q * 50 + t], xc[(size_t)t * B_D], s);
    __syncthreads();          // part's beta contents fully consumed earlier
    part[q][d] = s;
  }
  __syncthreads();
  if (tid < B_D) {
    out[(size_t)b * B_D + tid] = part[0][tid] + part[1][tid] + part[2][tid] + part[3][tid];
  }
}

extern "C" void kernel_launch(void* const* d_in, const int* in_sizes, int n_in,
                              void* d_out, int out_size, void* d_ws, size_t ws_size,
                              hipStream_t stream) {
  const float* x    = (const float*)d_in[0];
  const float* cand = (const float*)d_in[1];
  const void*  mask = d_in[2];
  const float* W1   = (const float*)d_in[3];
  const float* b1   = (const float*)d_in[4];
  const float* a    = (const float*)d_in[5];
  const float* W2   = (const float*)d_in[6];
  const float* b2   = (const float*)d_in[7];
  float* out = (float*)d_out;
  const int B = in_sizes[1] / B_D;   // candidate is [B,128]
  ta_fused<<<B, 512, 0, stream>>>(x, cand, mask, W1, b1, a, W2, b2, out);
}